// Round 2
// baseline (365.959 us; speedup 1.0000x reference)
//
#include <hip/hip_runtime.h>

// NeuralRodriguesOperator: B=512, C_L_in=C_L_out=64, C_J=16, 4x4 matrices.
// out[b,j,p,r] = sum_{i,q} F[b,i,p,q]*U[b,j,i,q,r] + Ub[b,j,i,p,q]*F[b,i,q,r]
// U  = W_bias  + sum_c W_cos[j,i,c]*cos(theta[b,c]) + W_sin[j,i,c]*sin(theta[b,c])
//
// R2 structure: lane = b (wave-uniform weight addrs -> s_load broadcast, weights
// ride the scalar pipe). 2048 blocks of 256 (= 8 blocks/CU, 32 waves/CU) to bury
// SMEM latency. Within a block: wave w = i-chunk of 4; LDS-reduce the 4 chunks
// (rows padded to 17 floats -> conflict-free); atomicAdd across the 4 i-splits.
// Block order swizzled so the 8 bgroup-blocks sharing weights sit on one XCD.

#define NRO_B   512
#define NRO_CL  64
#define NRO_CJ  16

__global__ __launch_bounds__(256) void nro_main_kernel(
    const float* __restrict__ F_in,     // (B, CL, 4, 4)
    const float* __restrict__ theta,    // (B, CJ)
    const float* __restrict__ W_bias,   // (CL, CL, 4, 4)
    const float* __restrict__ W_cos,    // (CL, CL, CJ, 4, 4)
    const float* __restrict__ W_sin,
    const float* __restrict__ Wb_bias,
    const float* __restrict__ Wb_cos,
    const float* __restrict__ Wb_sin,
    float* __restrict__ out)            // (B, CL, 4, 4), pre-zeroed
{
    // grid.x = j*4 + isplit (256), grid.y = bgroup (8).
    // Blocks sharing (j,isplit) [same weight slices] differ by 256 in flat id
    // -> same (id % 8) -> same XCD under round-robin dispatch.
    const int j      = blockIdx.x >> 2;
    const int isplit = blockIdx.x & 3;
    const int lane   = threadIdx.x & 63;          // b within group
    const int chunk  = threadIdx.x >> 6;          // wave id 0..3 = i-chunk
    const int b      = blockIdx.y * 64 + lane;
    const int ibase  = isplit * 16 + chunk * 4;   // 4 i's per thread

    // Per-lane cos/sin of theta[b, :]
    float csc[NRO_CJ], css[NRO_CJ];
    #pragma unroll
    for (int c = 0; c < NRO_CJ; ++c) {
        float t = theta[b * NRO_CJ + c];
        csc[c] = __cosf(t);
        css[c] = __sinf(t);
    }

    float acc[16];
    #pragma unroll
    for (int e = 0; e < 16; ++e) acc[e] = 0.0f;

    for (int ii = 0; ii < 4; ++ii) {
        const int i  = ibase + ii;
        const int ji = j * NRO_CL + i;

        // Wave-uniform weight slices for this (j, i)
        const float* __restrict__ wb  = W_bias  + ji * 16;
        const float* __restrict__ wbb = Wb_bias + ji * 16;
        const float* __restrict__ wc  = W_cos   + ji * 256;
        const float* __restrict__ wsn = W_sin   + ji * 256;
        const float* __restrict__ wbc = Wb_cos  + ji * 256;
        const float* __restrict__ wbs = Wb_sin  + ji * 256;

        // Per-lane F tile: F[b, i, :, :] (16 contiguous floats) — issue early
        float f[16];
        const float4* fp = (const float4*)(F_in + (b * NRO_CL + i) * 16);
        #pragma unroll
        for (int v = 0; v < 4; ++v) {
            float4 x = fp[v];
            f[v * 4 + 0] = x.x; f[v * 4 + 1] = x.y;
            f[v * 4 + 2] = x.z; f[v * 4 + 3] = x.w;
        }

        // Build U, Ub for this (b, j, i)
        float U[16], Ub[16];
        #pragma unroll
        for (int e = 0; e < 16; ++e) { U[e] = wb[e]; Ub[e] = wbb[e]; }

        #pragma unroll 4
        for (int c = 0; c < NRO_CJ; ++c) {
            const float cc = csc[c];
            const float ss = css[c];
            #pragma unroll
            for (int e = 0; e < 16; ++e) {
                U[e]  = fmaf(wc [c * 16 + e], cc, U[e]);
                U[e]  = fmaf(wsn[c * 16 + e], ss, U[e]);
                Ub[e] = fmaf(wbc[c * 16 + e], cc, Ub[e]);
                Ub[e] = fmaf(wbs[c * 16 + e], ss, Ub[e]);
            }
        }

        // acc[p,r] += sum_q F[p,q]*U[q,r] + Ub[p,q]*F[q,r]
        #pragma unroll
        for (int p = 0; p < 4; ++p) {
            #pragma unroll
            for (int r = 0; r < 4; ++r) {
                float a = acc[p * 4 + r];
                #pragma unroll
                for (int q = 0; q < 4; ++q) {
                    a = fmaf(f[p * 4 + q],  U[q * 4 + r], a);
                    a = fmaf(Ub[p * 4 + q], f[q * 4 + r], a);
                }
                acc[p * 4 + r] = a;
            }
        }
    }

    // In-block reduction over the 4 i-chunks (waves). Rows padded to 17
    // floats: for fixed e, lane l hits bank (17*l+e)%32 -> all 32 banks,
    // 2-way alias only (free on CDNA4).
    __shared__ float red[3][64][17];
    if (chunk > 0) {
        #pragma unroll
        for (int e = 0; e < 16; ++e) red[chunk - 1][lane][e] = acc[e];
    }
    __syncthreads();
    if (chunk == 0) {
        #pragma unroll
        for (int cc = 0; cc < 3; ++cc)
            #pragma unroll
            for (int e = 0; e < 16; ++e) acc[e] += red[cc][lane][e];

        // Cross-block (i-split) accumulation
        float* o = out + (b * NRO_CL + j) * 16;
        #pragma unroll
        for (int e = 0; e < 16; ++e) atomicAdd(o + e, acc[e]);
    }
}

extern "C" void kernel_launch(void* const* d_in, const int* in_sizes, int n_in,
                              void* d_out, int out_size, void* d_ws, size_t ws_size,
                              hipStream_t stream) {
    const float* F_in    = (const float*)d_in[0];
    const float* theta   = (const float*)d_in[1];
    const float* W_bias  = (const float*)d_in[2];
    const float* W_cos   = (const float*)d_in[3];
    const float* W_sin   = (const float*)d_in[4];
    const float* Wb_bias = (const float*)d_in[5];
    const float* Wb_cos  = (const float*)d_in[6];
    const float* Wb_sin  = (const float*)d_in[7];
    float* out = (float*)d_out;

    // out is re-poisoned before every timed launch; atomics need zeros.
    hipMemsetAsync(out, 0, (size_t)out_size * sizeof(float), stream);

    dim3 grid(NRO_CL * 4, NRO_B / 64, 1);   // x=(j,isplit), y=bgroup -> 2048 blocks
    nro_main_kernel<<<grid, 256, 0, stream>>>(
        F_in, theta, W_bias, W_cos, W_sin, Wb_bias, Wb_cos, Wb_sin, out);
}

// Round 3
// 245.631 us; speedup vs baseline: 1.4899x; 1.4899x over previous
//
#include <hip/hip_runtime.h>

// NeuralRodriguesOperator: B=512, C_L_in=C_L_out=64, C_J=16, 4x4 matrices.
// out[b,j,p,r] = sum_{i,q} F[b,i,p,q]*U[b,j,i,q,r] + Ub[b,j,i,p,q]*F[b,i,q,r]
// U  = W_bias  + sum_c W_cos[j,i,c]*cos(theta[b,c]) + W_sin[j,i,c]*sin(theta[b,c])
//
// R3 structure: lane = b; weight addresses depend only on (j, isplit, chunk)
// where chunk is forced wave-uniform via readfirstlane -> weights ride the
// scalar pipe (s_load broadcast), VALU does only FMAs. 2048 blocks of 256
// (8 blocks/CU, 32 waves/CU) bury SMEM latency. Wave w = i-chunk of 4;
// LDS-reduce the 4 chunks (rows padded to 17 -> conflict-free); atomicAdd
// across the 4 i-splits.
//
// R2 lesson (counters): chunk = threadIdx.x>>6 without readfirstlane is
// divergent to the compiler -> per-lane global_load of uniform weight addrs
// (SGPR 112->32, VALUBusy stuck at 12%). readfirstlane restores s_load.

#define NRO_B   512
#define NRO_CL  64
#define NRO_CJ  16

__global__ __launch_bounds__(256) void nro_main_kernel(
    const float* __restrict__ F_in,     // (B, CL, 4, 4)
    const float* __restrict__ theta,    // (B, CJ)
    const float* __restrict__ W_bias,   // (CL, CL, 4, 4)
    const float* __restrict__ W_cos,    // (CL, CL, CJ, 4, 4)
    const float* __restrict__ W_sin,
    const float* __restrict__ Wb_bias,
    const float* __restrict__ Wb_cos,
    const float* __restrict__ Wb_sin,
    float* __restrict__ out)            // (B, CL, 4, 4), pre-zeroed
{
    const int j      = blockIdx.x >> 2;           // scalar
    const int isplit = blockIdx.x & 3;            // scalar
    const int lane   = threadIdx.x & 63;          // b within group (divergent)
    // Wave id: uniform in reality; readfirstlane makes it uniform to LLVM so
    // all weight addressing stays in SGPRs.
    const int chunk  = __builtin_amdgcn_readfirstlane(threadIdx.x >> 6); // 0..3
    const int b      = blockIdx.y * 64 + lane;
    const int ibase  = isplit * 16 + chunk * 4;   // scalar: 4 i's per wave

    // Per-lane cos/sin of theta[b, :]
    float csc[NRO_CJ], css[NRO_CJ];
    #pragma unroll
    for (int c = 0; c < NRO_CJ; ++c) {
        float t = theta[b * NRO_CJ + c];
        csc[c] = __cosf(t);
        css[c] = __sinf(t);
    }

    float acc[16];
    #pragma unroll
    for (int e = 0; e < 16; ++e) acc[e] = 0.0f;

    for (int ii = 0; ii < 4; ++ii) {
        const int i  = ibase + ii;                // scalar
        const int ji = j * NRO_CL + i;            // scalar

        // Wave-uniform (scalar) weight slices for this (j, i)
        const float* __restrict__ wb  = W_bias  + ji * 16;
        const float* __restrict__ wbb = Wb_bias + ji * 16;
        const float* __restrict__ wc  = W_cos   + ji * 256;
        const float* __restrict__ wsn = W_sin   + ji * 256;
        const float* __restrict__ wbc = Wb_cos  + ji * 256;
        const float* __restrict__ wbs = Wb_sin  + ji * 256;

        // Per-lane F tile: F[b, i, :, :] (16 contiguous floats) — issue early
        float f[16];
        const float4* fp = (const float4*)(F_in + (b * NRO_CL + i) * 16);
        #pragma unroll
        for (int v = 0; v < 4; ++v) {
            float4 x = fp[v];
            f[v * 4 + 0] = x.x; f[v * 4 + 1] = x.y;
            f[v * 4 + 2] = x.z; f[v * 4 + 3] = x.w;
        }

        // Build U, Ub for this (b, j, i)
        float U[16], Ub[16];
        #pragma unroll
        for (int e = 0; e < 16; ++e) { U[e] = wb[e]; Ub[e] = wbb[e]; }

        #pragma unroll 4
        for (int c = 0; c < NRO_CJ; ++c) {
            const float cc = csc[c];
            const float ss = css[c];
            #pragma unroll
            for (int e = 0; e < 16; ++e) {
                U[e]  = fmaf(wc [c * 16 + e], cc, U[e]);
                U[e]  = fmaf(wsn[c * 16 + e], ss, U[e]);
                Ub[e] = fmaf(wbc[c * 16 + e], cc, Ub[e]);
                Ub[e] = fmaf(wbs[c * 16 + e], ss, Ub[e]);
            }
        }

        // acc[p,r] += sum_q F[p,q]*U[q,r] + Ub[p,q]*F[q,r]
        #pragma unroll
        for (int p = 0; p < 4; ++p) {
            #pragma unroll
            for (int r = 0; r < 4; ++r) {
                float a = acc[p * 4 + r];
                #pragma unroll
                for (int q = 0; q < 4; ++q) {
                    a = fmaf(f[p * 4 + q],  U[q * 4 + r], a);
                    a = fmaf(Ub[p * 4 + q], f[q * 4 + r], a);
                }
                acc[p * 4 + r] = a;
            }
        }
    }

    // In-block reduction over the 4 i-chunks (waves). Rows padded to 17
    // floats: for fixed e, lane l hits bank (17*l+e)%32 -> 2-way alias only
    // (free on CDNA4).
    __shared__ float red[3][64][17];
    if (chunk > 0) {
        #pragma unroll
        for (int e = 0; e < 16; ++e) red[chunk - 1][lane][e] = acc[e];
    }
    __syncthreads();
    if (chunk == 0) {
        #pragma unroll
        for (int cc = 0; cc < 3; ++cc)
            #pragma unroll
            for (int e = 0; e < 16; ++e) acc[e] += red[cc][lane][e];

        // Cross-block (i-split) accumulation
        float* o = out + (b * NRO_CL + j) * 16;
        #pragma unroll
        for (int e = 0; e < 16; ++e) atomicAdd(o + e, acc[e]);
    }
}

extern "C" void kernel_launch(void* const* d_in, const int* in_sizes, int n_in,
                              void* d_out, int out_size, void* d_ws, size_t ws_size,
                              hipStream_t stream) {
    const float* F_in    = (const float*)d_in[0];
    const float* theta   = (const float*)d_in[1];
    const float* W_bias  = (const float*)d_in[2];
    const float* W_cos   = (const float*)d_in[3];
    const float* W_sin   = (const float*)d_in[4];
    const float* Wb_bias = (const float*)d_in[5];
    const float* Wb_cos  = (const float*)d_in[6];
    const float* Wb_sin  = (const float*)d_in[7];
    float* out = (float*)d_out;

    // out is re-poisoned before every timed launch; atomics need zeros.
    hipMemsetAsync(out, 0, (size_t)out_size * sizeof(float), stream);

    dim3 grid(NRO_CL * 4, NRO_B / 64, 1);   // x=(j,isplit), y=bgroup -> 2048 blocks
    nro_main_kernel<<<grid, 256, 0, stream>>>(
        F_in, theta, W_bias, W_cos, W_sin, Wb_bias, Wb_cos, Wb_sin, out);
}

// Round 4
// 180.025 us; speedup vs baseline: 2.0328x; 1.3644x over previous
//
#include <hip/hip_runtime.h>

// NeuralRodriguesOperator: B=512, C_L_in=C_L_out=64, C_J=16, 4x4 matrices.
// out[b,j,p,r] = sum_{i,q} F[b,i,p,q]*U[b,j,i,q,r] + Ub[b,j,i,p,q]*F[b,i,q,r]
// U  = W_bias  + sum_c W_cos[j,i,c]*cos(theta[b,c]) + W_sin[j,i,c]*sin(theta[b,c])
//
// R4: weights through the VECTOR path. R3 counters proved the scalar pipe
// (s_load broadcast) can't stream 17 MB of weights: sL1D thrashes, few MSHRs,
// every wave serializes at L2 latency -> VALUBusy stuck at 20% (= 1-wave duty).
// Now: each block cooperatively stages its 33.8 KB weight slice into LDS with
// coalesced float4 loads, then all waves consume it as ds_read_b128 broadcasts
// (same-address -> conflict-free, ~1 LDS inst per 4 FMAs -> VALU-bound).
// Reduction: ws partials (plain stores) + tiny reduce kernel instead of
// atomics (R3's WRITE_SIZE=65MB amplification); atomic fallback if ws small.

#define NRO_B     512
#define NRO_CL    64
#define NRO_CJ    16
#define ISPLITS   8
#define IRANGE    8                          // i's per block
#define PART_ELEMS (NRO_B * NRO_CL * 16)     // 524288 floats per isplit partial

// LDS float layout (8448 floats = 33792 B):
//   wb  [0,128)  wbb [128,256)  wc [256,2304)  wsn [2304,4352)
//   wbc [4352,6400)  wbs [6400,8448)
// After compute, [0,3264) is reused (stride-17 padded) for the chunk reduction.

__global__ __launch_bounds__(256, 2) void nro_main_kernel(
    const float* __restrict__ F_in,     // (B, CL, 4, 4)
    const float* __restrict__ theta,    // (B, CJ)
    const float* __restrict__ W_bias,   // (CL, CL, 4, 4)
    const float* __restrict__ W_cos,    // (CL, CL, CJ, 4, 4)
    const float* __restrict__ W_sin,
    const float* __restrict__ Wb_bias,
    const float* __restrict__ Wb_cos,
    const float* __restrict__ Wb_sin,
    float* __restrict__ out,            // (B, CL, 4, 4) — atomic fallback path
    float* __restrict__ part,           // ws: (ISPLITS, B, CL, 4, 4)
    int use_ws)
{
    __shared__ float smem[8448];

    const int j      = blockIdx.x >> 3;                    // scalar
    const int isplit = blockIdx.x & 7;                     // scalar
    const int i0     = isplit * IRANGE;
    const int lane   = threadIdx.x & 63;                   // b within group
    const int chunk  = __builtin_amdgcn_readfirstlane(threadIdx.x >> 6); // 0..3
    const int b      = blockIdx.y * 64 + lane;
    const int tid    = threadIdx.x;

    // ---- cooperative weight staging (coalesced float4, vector path) ----
    {
        float4* s4 = (float4*)smem;
        const int base16  = (j * NRO_CL + i0) * 16;   // bias slices, contiguous
        const int base256 = (j * NRO_CL + i0) * 256;  // big slices, contiguous
        if (tid < 32) {
            s4[tid] = ((const float4*)(W_bias + base16))[tid];
        } else if (tid < 64) {
            s4[tid] = ((const float4*)(Wb_bias + base16))[tid - 32];
        }
        const float4* gc  = (const float4*)(W_cos  + base256);
        const float4* gs  = (const float4*)(W_sin  + base256);
        const float4* gbc = (const float4*)(Wb_cos + base256);
        const float4* gbs = (const float4*)(Wb_sin + base256);
        #pragma unroll
        for (int r = 0; r < 2; ++r) {
            const int k = r * 256 + tid;               // 512 f4 per big array
            s4[64   + k] = gc[k];
            s4[576  + k] = gs[k];
            s4[1088 + k] = gbc[k];
            s4[1600 + k] = gbs[k];
        }
    }

    // Per-lane cos/sin of theta[b, :] (overlaps with staging)
    float csc[NRO_CJ], css[NRO_CJ];
    #pragma unroll
    for (int c = 0; c < NRO_CJ; ++c) {
        float t = theta[b * NRO_CJ + c];
        csc[c] = __cosf(t);
        css[c] = __sinf(t);
    }

    __syncthreads();

    float acc[16];
    #pragma unroll
    for (int e = 0; e < 16; ++e) acc[e] = 0.0f;

    #pragma unroll
    for (int ii = 0; ii < 2; ++ii) {
        const int il = chunk * 2 + ii;          // local i: 0..7 (wave-uniform)
        const int i  = i0 + il;

        // Per-lane F tile (global, coalesced-ish 16B/lane)
        float f[16];
        const float4* fp = (const float4*)(F_in + (b * NRO_CL + i) * 16);
        #pragma unroll
        for (int v = 0; v < 4; ++v) {
            float4 x = fp[v];
            f[v*4+0] = x.x; f[v*4+1] = x.y; f[v*4+2] = x.z; f[v*4+3] = x.w;
        }

        // LDS slices for this i — all reads below are same-address broadcasts
        const float* wb  = smem + il * 16;
        const float* wbb = smem + 128  + il * 16;
        const float* wc  = smem + 256  + il * 256;
        const float* wsn = smem + 2304 + il * 256;
        const float* wbc = smem + 4352 + il * 256;
        const float* wbs = smem + 6400 + il * 256;

        float U[16], Ub[16];
        #pragma unroll
        for (int v = 0; v < 4; ++v) {
            float4 x = ((const float4*)wb)[v];
            float4 y = ((const float4*)wbb)[v];
            U[v*4+0]=x.x; U[v*4+1]=x.y; U[v*4+2]=x.z; U[v*4+3]=x.w;
            Ub[v*4+0]=y.x; Ub[v*4+1]=y.y; Ub[v*4+2]=y.z; Ub[v*4+3]=y.w;
        }

        #pragma unroll 4
        for (int c = 0; c < NRO_CJ; ++c) {
            const float cc = csc[c];
            const float ss = css[c];
            const float4* a4 = (const float4*)(wc  + c * 16);
            const float4* s4 = (const float4*)(wsn + c * 16);
            const float4* c4 = (const float4*)(wbc + c * 16);
            const float4* d4 = (const float4*)(wbs + c * 16);
            #pragma unroll
            for (int v = 0; v < 4; ++v) {
                float4 xw = a4[v], yw = s4[v], zw = c4[v], ww = d4[v];
                U [v*4+0] = fmaf(xw.x, cc, U [v*4+0]);
                U [v*4+1] = fmaf(xw.y, cc, U [v*4+1]);
                U [v*4+2] = fmaf(xw.z, cc, U [v*4+2]);
                U [v*4+3] = fmaf(xw.w, cc, U [v*4+3]);
                U [v*4+0] = fmaf(yw.x, ss, U [v*4+0]);
                U [v*4+1] = fmaf(yw.y, ss, U [v*4+1]);
                U [v*4+2] = fmaf(yw.z, ss, U [v*4+2]);
                U [v*4+3] = fmaf(yw.w, ss, U [v*4+3]);
                Ub[v*4+0] = fmaf(zw.x, cc, Ub[v*4+0]);
                Ub[v*4+1] = fmaf(zw.y, cc, Ub[v*4+1]);
                Ub[v*4+2] = fmaf(zw.z, cc, Ub[v*4+2]);
                Ub[v*4+3] = fmaf(zw.w, cc, Ub[v*4+3]);
                Ub[v*4+0] = fmaf(ww.x, ss, Ub[v*4+0]);
                Ub[v*4+1] = fmaf(ww.y, ss, Ub[v*4+1]);
                Ub[v*4+2] = fmaf(ww.z, ss, Ub[v*4+2]);
                Ub[v*4+3] = fmaf(ww.w, ss, Ub[v*4+3]);
            }
        }

        // acc[p,r] += sum_q F[p,q]*U[q,r] + Ub[p,q]*F[q,r]
        #pragma unroll
        for (int p = 0; p < 4; ++p) {
            #pragma unroll
            for (int r = 0; r < 4; ++r) {
                float a = acc[p*4+r];
                #pragma unroll
                for (int q = 0; q < 4; ++q) {
                    a = fmaf(f[p*4+q],  U[q*4+r], a);
                    a = fmaf(Ub[p*4+q], f[q*4+r], a);
                }
                acc[p*4+r] = a;
            }
        }
    }

    // ---- in-block reduction over the 4 i-chunks (reuse weight LDS) ----
    __syncthreads();                 // all waves done reading weights
    if (chunk > 0) {
        float* r = smem + (chunk - 1) * 1088 + lane * 17;  // stride 17: 2-way max
        #pragma unroll
        for (int e = 0; e < 16; ++e) r[e] = acc[e];
    }
    __syncthreads();
    if (chunk == 0) {
        #pragma unroll
        for (int cc = 0; cc < 3; ++cc) {
            const float* r = smem + cc * 1088 + lane * 17;
            #pragma unroll
            for (int e = 0; e < 16; ++e) acc[e] += r[e];
        }
        if (use_ws) {
            float4* o = (float4*)(part + ((size_t)(isplit * NRO_B + b) * NRO_CL + j) * 16);
            o[0] = make_float4(acc[0],  acc[1],  acc[2],  acc[3]);
            o[1] = make_float4(acc[4],  acc[5],  acc[6],  acc[7]);
            o[2] = make_float4(acc[8],  acc[9],  acc[10], acc[11]);
            o[3] = make_float4(acc[12], acc[13], acc[14], acc[15]);
        } else {
            float* o = out + ((size_t)b * NRO_CL + j) * 16;
            #pragma unroll
            for (int e = 0; e < 16; ++e) atomicAdd(o + e, acc[e]);
        }
    }
}

__global__ __launch_bounds__(256) void nro_reduce_kernel(
    const float* __restrict__ part, float* __restrict__ out)
{
    const int idx = blockIdx.x * 256 + threadIdx.x;   // 524288 total
    float s = 0.0f;
    #pragma unroll
    for (int p = 0; p < ISPLITS; ++p) s += part[(size_t)p * PART_ELEMS + idx];
    out[idx] = s;
}

extern "C" void kernel_launch(void* const* d_in, const int* in_sizes, int n_in,
                              void* d_out, int out_size, void* d_ws, size_t ws_size,
                              hipStream_t stream) {
    const float* F_in    = (const float*)d_in[0];
    const float* theta   = (const float*)d_in[1];
    const float* W_bias  = (const float*)d_in[2];
    const float* W_cos   = (const float*)d_in[3];
    const float* W_sin   = (const float*)d_in[4];
    const float* Wb_bias = (const float*)d_in[5];
    const float* Wb_cos  = (const float*)d_in[6];
    const float* Wb_sin  = (const float*)d_in[7];
    float* out  = (float*)d_out;
    float* part = (float*)d_ws;

    const size_t need = (size_t)ISPLITS * PART_ELEMS * sizeof(float); // 16.78 MB
    const int use_ws = (ws_size >= need) ? 1 : 0;

    if (!use_ws) {
        // atomic fallback needs zeroed output
        hipMemsetAsync(out, 0, (size_t)out_size * sizeof(float), stream);
    }

    dim3 grid(NRO_CL * ISPLITS, NRO_B / 64, 1);   // (j,isplit) x bgroup = 4096 blocks
    nro_main_kernel<<<grid, 256, 0, stream>>>(
        F_in, theta, W_bias, W_cos, W_sin, Wb_bias, Wb_cos, Wb_sin,
        out, part, use_ws);

    if (use_ws) {
        nro_reduce_kernel<<<PART_ELEMS / 256, 256, 0, stream>>>(part, out);
    }
}